// Round 1
// baseline (673.944 us; speedup 1.0000x reference)
//
#include <hip/hip_runtime.h>

// Problem constants
#define T_TOK 1024
#define HID   1024
#define NE    64
#define TOPKK 8
#define ITR   768
#define CAP   256

typedef __attribute__((ext_vector_type(4))) float f32x4;
typedef __attribute__((ext_vector_type(8))) short s16x8;

// ---- workspace layout (bytes) ----
// counts @0 (256B) | topki @1024 (32KB) | slot_of (32KB) | topkw (32KB) | etok (64KB)
// Xd bf16 [NE][CAP][HID] @256KiB (33.5MB)  | G bf16 [NE][CAP][ITR] (25.2MB)
// Y bf16 [NE][CAP][HID] aliases Xd (Xd dead after gemm1)
#define OFF_COUNTS 0
#define OFF_TOPKI  1024
#define OFF_SLOT   (OFF_TOPKI + T_TOK*TOPKK*4)
#define OFF_TOPKW  (OFF_SLOT  + T_TOK*TOPKK*4)
#define OFF_ETOK   (OFF_TOPKW + T_TOK*TOPKK*4)
#define OFF_XD     (1 << 18)
#define OFF_G      (OFF_XD + (size_t)NE*CAP*HID*2)
#define OFF_Y      OFF_XD

__device__ __forceinline__ unsigned short f2bf(float f) {
  union { float f; unsigned u; } v; v.f = f;
  unsigned r = v.u + 0x7FFFu + ((v.u >> 16) & 1u);   // RNE
  return (unsigned short)(r >> 16);
}
__device__ __forceinline__ float bf2f(unsigned short h) {
  union { unsigned u; float f; } v; v.u = ((unsigned)h) << 16;
  return v.f;
}
__device__ __forceinline__ unsigned pack2(float a, float b) {
  return (unsigned)f2bf(a) | ((unsigned)f2bf(b) << 16);
}

// ---------------- router: fp64 logits -> softmax -> top8 -> renorm ----------------
__global__ __launch_bounds__(256) void router_k(
    const float* __restrict__ x, const float* __restrict__ gw,
    int* __restrict__ topki, float* __restrict__ topkw, int* __restrict__ counts)
{
  int t = blockIdx.x, tid = threadIdx.x;
  if (t == 0 && tid < NE) counts[tid] = 0;   // zero before assign_k (next kernel)
  __shared__ float xs[HID];
  __shared__ double parts[4 * 64];
  *(f32x4*)&xs[tid * 4] = *(const f32x4*)(x + (size_t)t * HID + tid * 4);
  __syncthreads();
  int e = tid & 63, part = tid >> 6;
  const float* g  = gw + (size_t)e * HID + part * 256;
  const float* xp = xs + part * 256;
  double acc = 0.0;
  #pragma unroll 4
  for (int h = 0; h < 256; h += 4) {
    f32x4 gv = *(const f32x4*)(g + h);
    f32x4 xv = *(const f32x4*)(xp + h);
    acc += (double)xv.x * gv.x + (double)xv.y * gv.y
         + (double)xv.z * gv.z + (double)xv.w * gv.w;
  }
  parts[part * 64 + e] = acc;
  __syncthreads();
  if (tid < 64) {
    double l = parts[tid] + parts[64 + tid] + parts[128 + tid] + parts[192 + tid];
    double m = l;
    for (int off = 32; off >= 1; off >>= 1) {
      double o = __shfl_xor(m, off, 64);
      m = o > m ? o : m;
    }
    double p  = exp(l - m);   // softmax normalizer cancels in top-8 renorm
    double pv = p;
    double wv[TOPKK]; int wi[TOPKK];
    double sum8 = 0.0;
    #pragma unroll
    for (int j = 0; j < TOPKK; ++j) {
      double bv = pv; int bi = tid;
      for (int off = 32; off >= 1; off >>= 1) {
        double ov = __shfl_xor(bv, off, 64);
        int    oi = __shfl_xor(bi, off, 64);
        if (ov > bv || (ov == bv && oi < bi)) { bv = ov; bi = oi; }  // lax.top_k tiebreak
      }
      wv[j] = bv; wi[j] = bi; sum8 += bv;
      if (tid == bi) pv = -1.0;
    }
    if (tid == 0) {
      double inv = 1.0 / sum8;
      #pragma unroll
      for (int j = 0; j < TOPKK; ++j) {
        topki[t * TOPKK + j] = wi[j];
        topkw[t * TOPKK + j] = (float)(wv[j] * inv);
      }
    }
  }
}

// ---------------- slot assignment (atomic; permutation is arithmetically inert) ----
__global__ __launch_bounds__(256) void assign_k(
    const int* __restrict__ topki, int* __restrict__ counts,
    int* __restrict__ slot_of, int* __restrict__ etok)
{
  int a = blockIdx.x * 256 + threadIdx.x;
  if (a >= T_TOK * TOPKK) return;
  int e = topki[a];
  int s = atomicAdd(counts + e, 1);
  if (s < CAP) { slot_of[a] = s; etok[e * CAP + s] = a >> 3; }
  else         { slot_of[a] = -1; }
}

// ---------------- gather token rows into per-expert bf16 buffer ----------------
__global__ __launch_bounds__(128) void dispatch_k(
    const float* __restrict__ x, const int* __restrict__ counts,
    const int* __restrict__ etok, unsigned short* __restrict__ Xd)
{
  int b = blockIdx.x;
  int e = b >> 8, s = b & 255;
  int cnt = min(counts[e], CAP);
  if (s >= cnt) return;
  int t = etok[b];
  const float* src = x + (size_t)t * HID;
  unsigned short* dst = Xd + (size_t)b * HID;
  int tid = threadIdx.x;
  #pragma unroll
  for (int i = 0; i < 2; ++i) {
    int h = (tid + i * 128) * 4;
    f32x4 v = *(const f32x4*)(src + h);
    ushort4 o;
    o.x = f2bf(v.x); o.y = f2bf(v.y); o.z = f2bf(v.z); o.w = f2bf(v.w);
    *(ushort4*)(dst + h) = o;
  }
}

// ---------------- GEMM1: G = silu(Xd Wg^T) * (Xd Wu^T), bf16 MFMA ----------------
// block tile 128 rows x 64 cols, both matrices; BK=64; LDS rows padded to 72 elems.
__global__ __launch_bounds__(256) void gemm1_k(
    const unsigned short* __restrict__ Xd, const float* __restrict__ wg,
    const float* __restrict__ wu, const int* __restrict__ counts,
    unsigned short* __restrict__ G)
{
  int bx = blockIdx.x;
  int rt = bx & 1;
  int tmp = bx >> 1;
  int ct = tmp % 12;
  int e  = tmp / 12;
  int cnt = min(counts[e], CAP);
  if (rt * 128 >= cnt) return;

  __shared__ unsigned short As[128 * 72];
  __shared__ unsigned short Bg[64 * 72];
  __shared__ unsigned short Bu[64 * 72];

  int tid = threadIdx.x;
  int lane = tid & 63, w = tid >> 6;
  int wm = w & 1, wn = w >> 1;   // wave tile: 64 rows x 32 cols

  const unsigned short* Abase = Xd + ((size_t)e * CAP + rt * 128) * HID;
  const float* gbase = wg + ((size_t)e * ITR + ct * 64) * HID;
  const float* ubase = wu + ((size_t)e * ITR + ct * 64) * HID;

  f32x4 accg[4][2], accu[4][2];
  #pragma unroll
  for (int i = 0; i < 4; ++i)
    #pragma unroll
    for (int j = 0; j < 2; ++j) { accg[i][j] = (f32x4)0.0f; accu[i][j] = (f32x4)0.0f; }

  for (int kc = 0; kc < HID / 64; ++kc) {
    int k0 = kc * 64;
    __syncthreads();
    // stage A: 128x64 bf16 (1024 x 16B segs)
    #pragma unroll
    for (int i = 0; i < 4; ++i) {
      int seg = tid + i * 256;
      int r = seg >> 3, s = seg & 7;
      uint4 v = *(const uint4*)(Abase + (size_t)r * HID + k0 + s * 8);
      *(uint4*)&As[r * 72 + s * 8] = v;
    }
    // stage Bg/Bu: 64x64 fp32 -> bf16 (512 segs each)
    #pragma unroll
    for (int i = 0; i < 2; ++i) {
      int seg = tid + i * 256;
      int r = seg >> 3, s = seg & 7;
      const float* p = gbase + (size_t)r * HID + k0 + s * 8;
      f32x4 v0 = *(const f32x4*)p;
      f32x4 v1 = *(const f32x4*)(p + 4);
      uint4 pk;
      pk.x = pack2(v0.x, v0.y); pk.y = pack2(v0.z, v0.w);
      pk.z = pack2(v1.x, v1.y); pk.w = pack2(v1.z, v1.w);
      *(uint4*)&Bg[r * 72 + s * 8] = pk;
      p = ubase + (size_t)r * HID + k0 + s * 8;
      v0 = *(const f32x4*)p;
      v1 = *(const f32x4*)(p + 4);
      pk.x = pack2(v0.x, v0.y); pk.y = pack2(v0.z, v0.w);
      pk.z = pack2(v1.x, v1.y); pk.w = pack2(v1.z, v1.w);
      *(uint4*)&Bu[r * 72 + s * 8] = pk;
    }
    __syncthreads();
    #pragma unroll
    for (int ks = 0; ks < 2; ++ks) {
      s16x8 af[4];
      #pragma unroll
      for (int mt = 0; mt < 4; ++mt)
        af[mt] = *(const s16x8*)&As[(wm * 64 + mt * 16 + (lane & 15)) * 72 + ks * 32 + (lane >> 4) * 8];
      s16x8 bgf[2], buf_[2];
      #pragma unroll
      for (int nt = 0; nt < 2; ++nt) {
        int r = wn * 32 + nt * 16 + (lane & 15);
        bgf[nt]  = *(const s16x8*)&Bg[r * 72 + ks * 32 + (lane >> 4) * 8];
        buf_[nt] = *(const s16x8*)&Bu[r * 72 + ks * 32 + (lane >> 4) * 8];
      }
      #pragma unroll
      for (int mt = 0; mt < 4; ++mt)
        #pragma unroll
        for (int nt = 0; nt < 2; ++nt) {
          accg[mt][nt] = __builtin_amdgcn_mfma_f32_16x16x32_bf16(af[mt], bgf[nt],  accg[mt][nt], 0, 0, 0);
          accu[mt][nt] = __builtin_amdgcn_mfma_f32_16x16x32_bf16(af[mt], buf_[nt], accu[mt][nt], 0, 0, 0);
        }
    }
  }
  // epilogue: silu(g)*u -> bf16  (C/D map: col=lane&15, row=(lane>>4)*4+reg)
  int rowb = rt * 128 + wm * 64;
  int colb = ct * 64 + wn * 32;
  unsigned short* Gout = G + (size_t)e * CAP * ITR;
  #pragma unroll
  for (int mt = 0; mt < 4; ++mt)
    #pragma unroll
    for (int nt = 0; nt < 2; ++nt)
      #pragma unroll
      for (int r = 0; r < 4; ++r) {
        int row = rowb + mt * 16 + (lane >> 4) * 4 + r;
        int col = colb + nt * 16 + (lane & 15);
        float gv = accg[mt][nt][r];
        float uv = accu[mt][nt][r];
        float sg = gv / (1.0f + __expf(-gv));
        Gout[(size_t)row * ITR + col] = f2bf(sg * uv);
      }
}

// ---------------- GEMM2: Y = G Wd^T ----------------
__global__ __launch_bounds__(256) void gemm2_k(
    const unsigned short* __restrict__ G, const float* __restrict__ wd,
    const int* __restrict__ counts, unsigned short* __restrict__ Y)
{
  int bx = blockIdx.x;
  int rt = bx & 1;
  int tmp = bx >> 1;
  int ct = tmp & 15;
  int e  = tmp >> 4;
  int cnt = min(counts[e], CAP);
  if (rt * 128 >= cnt) return;

  __shared__ unsigned short As[128 * 72];
  __shared__ unsigned short Bs[64 * 72];

  int tid = threadIdx.x;
  int lane = tid & 63, w = tid >> 6;
  int wm = w & 1, wn = w >> 1;

  const unsigned short* Abase = G + ((size_t)e * CAP + rt * 128) * ITR;
  const float* bbase = wd + ((size_t)e * HID + ct * 64) * ITR;

  f32x4 acc[4][2];
  #pragma unroll
  for (int i = 0; i < 4; ++i)
    #pragma unroll
    for (int j = 0; j < 2; ++j) acc[i][j] = (f32x4)0.0f;

  for (int kc = 0; kc < ITR / 64; ++kc) {
    int k0 = kc * 64;
    __syncthreads();
    #pragma unroll
    for (int i = 0; i < 4; ++i) {
      int seg = tid + i * 256;
      int r = seg >> 3, s = seg & 7;
      uint4 v = *(const uint4*)(Abase + (size_t)r * ITR + k0 + s * 8);
      *(uint4*)&As[r * 72 + s * 8] = v;
    }
    #pragma unroll
    for (int i = 0; i < 2; ++i) {
      int seg = tid + i * 256;
      int r = seg >> 3, s = seg & 7;
      const float* p = bbase + (size_t)r * ITR + k0 + s * 8;
      f32x4 v0 = *(const f32x4*)p;
      f32x4 v1 = *(const f32x4*)(p + 4);
      uint4 pk;
      pk.x = pack2(v0.x, v0.y); pk.y = pack2(v0.z, v0.w);
      pk.z = pack2(v1.x, v1.y); pk.w = pack2(v1.z, v1.w);
      *(uint4*)&Bs[r * 72 + s * 8] = pk;
    }
    __syncthreads();
    #pragma unroll
    for (int ks = 0; ks < 2; ++ks) {
      s16x8 af[4];
      #pragma unroll
      for (int mt = 0; mt < 4; ++mt)
        af[mt] = *(const s16x8*)&As[(wm * 64 + mt * 16 + (lane & 15)) * 72 + ks * 32 + (lane >> 4) * 8];
      s16x8 bf[2];
      #pragma unroll
      for (int nt = 0; nt < 2; ++nt) {
        int r = wn * 32 + nt * 16 + (lane & 15);
        bf[nt] = *(const s16x8*)&Bs[r * 72 + ks * 32 + (lane >> 4) * 8];
      }
      #pragma unroll
      for (int mt = 0; mt < 4; ++mt)
        #pragma unroll
        for (int nt = 0; nt < 2; ++nt)
          acc[mt][nt] = __builtin_amdgcn_mfma_f32_16x16x32_bf16(af[mt], bf[nt], acc[mt][nt], 0, 0, 0);
    }
  }
  int rowb = rt * 128 + wm * 64;
  int colb = ct * 64 + wn * 32;
  unsigned short* Yout = Y + (size_t)e * CAP * HID;
  #pragma unroll
  for (int mt = 0; mt < 4; ++mt)
    #pragma unroll
    for (int nt = 0; nt < 2; ++nt)
      #pragma unroll
      for (int r = 0; r < 4; ++r) {
        int row = rowb + mt * 16 + (lane >> 4) * 4 + r;
        int col = colb + nt * 16 + (lane & 15);
        Yout[(size_t)row * HID + col] = f2bf(acc[mt][nt][r]);
      }
}

// ---------------- combine: out[t] = sum_k w * Y[e_k, slot_k] ----------------
__global__ __launch_bounds__(256) void combine_k(
    const unsigned short* __restrict__ Y, const int* __restrict__ topki,
    const int* __restrict__ slot_of, const float* __restrict__ topkw,
    float* __restrict__ out)
{
  int t = blockIdx.x, tid = threadIdx.x;
  int h = tid * 4;
  float a0 = 0.f, a1 = 0.f, a2 = 0.f, a3 = 0.f;
  #pragma unroll
  for (int k = 0; k < TOPKK; ++k) {
    int a = t * TOPKK + k;
    int s = slot_of[a];
    if (s < 0) continue;
    int e = topki[a];
    float wt = topkw[a];
    const unsigned short* yp = Y + ((size_t)(e * CAP + s)) * HID + h;
    ushort4 yv = *(const ushort4*)yp;
    a0 += wt * bf2f(yv.x);
    a1 += wt * bf2f(yv.y);
    a2 += wt * bf2f(yv.z);
    a3 += wt * bf2f(yv.w);
  }
  f32x4 o = { a0, a1, a2, a3 };
  *(f32x4*)(out + (size_t)t * HID + h) = o;
}

extern "C" void kernel_launch(void* const* d_in, const int* in_sizes, int n_in,
                              void* d_out, int out_size, void* d_ws, size_t ws_size,
                              hipStream_t stream)
{
  const float* x     = (const float*)d_in[0];
  const float* gw    = (const float*)d_in[1];
  const float* wgate = (const float*)d_in[2];
  const float* wup   = (const float*)d_in[3];
  const float* wdown = (const float*)d_in[4];
  float* out = (float*)d_out;

  char* ws = (char*)d_ws;
  int*   counts  = (int*)  (ws + OFF_COUNTS);
  int*   topki   = (int*)  (ws + OFF_TOPKI);
  int*   slot_of = (int*)  (ws + OFF_SLOT);
  float* topkw   = (float*)(ws + OFF_TOPKW);
  int*   etok    = (int*)  (ws + OFF_ETOK);
  unsigned short* Xd = (unsigned short*)(ws + OFF_XD);
  unsigned short* G  = (unsigned short*)(ws + OFF_G);
  unsigned short* Y  = (unsigned short*)(ws + OFF_Y);  // aliases Xd (dead after gemm1)

  router_k  <<<T_TOK, 256, 0, stream>>>(x, gw, topki, topkw, counts);
  assign_k  <<<(T_TOK * TOPKK) / 256, 256, 0, stream>>>(topki, counts, slot_of, etok);
  dispatch_k<<<NE * CAP, 128, 0, stream>>>(x, counts, etok, Xd);
  gemm1_k   <<<NE * 12 * 2, 256, 0, stream>>>(Xd, wgate, wup, counts, G);
  gemm2_k   <<<NE * 16 * 2, 256, 0, stream>>>(G, wdown, counts, Y);
  combine_k <<<T_TOK, 256, 0, stream>>>(Y, topki, slot_of, topkw, out);
}